// Round 13
// baseline (2920.677 us; speedup 1.0000x reference)
//
#include <hip/hip_runtime.h>

#define BB 8
#define LL 2048
#define DD 512
#define QQ 8
#define KK 2048
#define MM (BB*LL)      // 16384 points

#define NTILES 16       // 16 col-tiles of 128

typedef __attribute__((ext_vector_type(8))) short short8;
typedef __attribute__((ext_vector_type(4))) float f32x4;

#define GLDS(src, dst) __builtin_amdgcn_global_load_lds( \
    (const __attribute__((address_space(1))) void*)(src), \
    (__attribute__((address_space(3))) void*)(dst), 16, 0, 0)

#define BARX()  asm volatile("s_barrier" ::: "memory")
#define WAIT0() asm volatile("s_waitcnt vmcnt(0)" ::: "memory")

__device__ __forceinline__ ushort f2bf(float f) {
    uint u = __float_as_uint(f);
    u += 0x7FFFu + ((u >> 16) & 1u);
    return (ushort)(u >> 16);
}

// ---------------- B prep ALL LEVELS once + fused squared norms ----------------
__global__ __launch_bounds__(256) void bprep_kernel(const float* __restrict__ cb,
                                                    short8* __restrict__ bh2all,
                                                    float* __restrict__ cb2) {
    const int wid  = threadIdx.x >> 6;
    const int lane = threadIdx.x & 63;
    const int col  = blockIdx.x * 4 + wid;      // 0 .. QQ*KK-1
    const float* src = cb + (size_t)col * DD + lane * 8;
    float4 v0 = *(const float4*)src;
    float4 v1 = *(const float4*)(src + 4);
    short8 h;
    h[0] = (short)f2bf(v0.x); h[1] = (short)f2bf(v0.y);
    h[2] = (short)f2bf(v0.z); h[3] = (short)f2bf(v0.w);
    h[4] = (short)f2bf(v1.x); h[5] = (short)f2bf(v1.y);
    h[6] = (short)f2bf(v1.z); h[7] = (short)f2bf(v1.w);
    bh2all[(size_t)col * 64 + lane] = h;
    float s = v0.x*v0.x + v0.y*v0.y + v0.z*v0.z + v0.w*v0.w
            + v1.x*v1.x + v1.y*v1.y + v1.z*v1.z + v1.w*v1.w;
    #pragma unroll
    for (int off = 32; off >= 1; off >>= 1) s += __shfl_xor(s, off);
    if (lane == 0) cb2[col] = s;
}

// ---------------- level-0 A prep: resid <- x, ah <- bf16(x) [row][lane] ----------------
__global__ __launch_bounds__(256) void aprep0_kernel(const float* __restrict__ x,
                                                     float* __restrict__ resid,
                                                     short8* __restrict__ ah) {
    const int wid  = threadIdx.x >> 6;
    const int lane = threadIdx.x & 63;
    const int row  = blockIdx.x * 4 + wid;
    const float* src = x + (size_t)row * DD + lane * 8;
    float4 v0 = *(const float4*)src;
    float4 v1 = *(const float4*)(src + 4);
    float* dst = resid + (size_t)row * DD + lane * 8;
    *(float4*)dst       = v0;
    *(float4*)(dst + 4) = v1;
    short8 h;
    h[0] = (short)f2bf(v0.x); h[1] = (short)f2bf(v0.y);
    h[2] = (short)f2bf(v0.z); h[3] = (short)f2bf(v0.w);
    h[4] = (short)f2bf(v1.x); h[5] = (short)f2bf(v1.y);
    h[6] = (short)f2bf(v1.z); h[7] = (short)f2bf(v1.w);
    ah[(size_t)row * 64 + lane] = h;
}

// ---------------- 256x256 BK=32 bf16 GEMM + per-tile (v1, mask) — 2 blocks/CU ----------------
// 512 blocks x 512 thr (8 waves 2Mx4N, wave tile 128x64), 16 K-tiles of BK=32.
// LDS 64 KB (2 buf x [A 16KB | B 16KB interleaved]) -> TWO blocks co-resident per CU
// (16 waves/CU): one block's vmcnt/barrier drains are hidden by the sibling's MFMAs.
// Same dual-XOR cell layout as r12 (ks term dropped); per-element K order = tile-
// ascending == r11/r12 -> masks bit-identical. __launch_bounds__(512,4) caps VGPR<=128.
__global__ __launch_bounds__(512, 4) void gemm_argmin_kernel(
    const short8* __restrict__ ah,
    const short8* __restrict__ bh2q,
    const float*  __restrict__ cb2q,
    float*        __restrict__ blockv1,    // [NTILES][MM]
    uint4*        __restrict__ blockmask,  // [NTILES][MM]
    float W)
{
    __shared__ char smemc[65536];   // [2 buf][256 pair-rows x 128B (A64|B64 interleaved)]

    const int id  = blockIdx.x;
    const int xcd = id & 7;
    const int s   = id >> 3;             // 0..63
    const int nt  = s & 7;               // 0..7 (256-col tiles)
    const int mt  = xcd * 8 + (s >> 3);  // 0..63 (256-row tiles), A reuse per XCD

    const int tid  = threadIdx.x;
    const int wid  = tid >> 6;
    const int lane = tid & 63;
    const int wr   = wid >> 2;           // rows [wr*128, +128)
    const int wcn  = wid & 3;            // cols [wcn*64, +64)
    const int l15  = lane & 15, l4 = lane >> 4;

    f32x4 acc[4][8];
    #pragma unroll
    for (int n = 0; n < 4; n++)
        #pragma unroll
        for (int m = 0; m < 8; m++) acc[n][m] = (f32x4){0.f, 0.f, 0.f, 0.f};

    const char* aSrc = (const char*)ah   + ((size_t)mt << 18);   // 256 rows x 1 KB
    const char* bSrc = (const char*)bh2q + ((size_t)nt << 18);

    // stage K-tile tt (64B/row) into buffer bufn: 4 GLDS/wave (32 KB total).
    // Cell (pr, isAB, slot<4) at pr*128 + (isAB ^ ((pr>>2)&1))*64 + ((slot^(pr&3))<<4)
    // (involution; r12-proven). LDS dest linear; source carries the inverse perm.
    #define STAGET(tt, bufn) do { \
        _Pragma("unroll") for (int j = 0; j < 4; j++) { \
            int g_  = wid * 4 + j; \
            int pr_ = g_ * 8 + (lane >> 3); \
            int isB_ = ((lane >> 2) & 1) ^ ((pr_ >> 2) & 1); \
            int sl_  = (lane & 3) ^ (pr_ & 3); \
            const char* s_ = (isB_ ? bSrc : aSrc) + (size_t)pr_ * 1024 \
                             + (tt) * 64 + sl_ * 16; \
            GLDS(s_, smemc + (bufn) * 32768 + g_ * 1024); \
        } } while (0)

    short8 af[8], bf[4];

    #define LDAB() do { \
        _Pragma("unroll") for (int mm = 0; mm < 8; mm++) { \
            int rL_ = wr * 128 + mm * 16 + l15; \
            af[mm] = *(const short8*)(smemc + ab + rL_ * 128 \
                     + (((rL_ >> 2) & 1) << 6) + ((l4 ^ (rL_ & 3)) << 4)); \
        } \
        _Pragma("unroll") for (int nn = 0; nn < 4; nn++) { \
            int cL_ = wcn * 64 + nn * 16 + l15; \
            bf[nn] = *(const short8*)(smemc + ab + cL_ * 128 \
                     + ((1 ^ ((cL_ >> 2) & 1)) << 6) + ((l4 ^ (cL_ & 3)) << 4)); \
        } } while (0)

    #define PHALL() do { \
        __builtin_amdgcn_s_setprio(1); \
        _Pragma("unroll") for (int nn = 0; nn < 4; nn++) \
        _Pragma("unroll") for (int mm = 0; mm < 8; mm++) \
            acc[nn][mm] = __builtin_amdgcn_mfma_f32_16x16x32_bf16( \
                bf[nn], af[mm], acc[nn][mm], 0, 0, 0); \
        __builtin_amdgcn_s_setprio(0); \
    } while (0)

    STAGET(0, 0);
    WAIT0();
    BARX();

    #pragma unroll
    for (int t = 0; t < 16; t++) {
        const uint ab = (uint)(t & 1) * 32768u;
        const int nbuf = (t & 1) ^ 1;
        if (t < 15) STAGET(t + 1, nbuf);
        LDAB();
        PHALL();
        if (t < 15) WAIT0();
        BARX();
    }

    // ---- mask epilogue (r11-verbatim; scratch at base; last tile read buf1 @32KB) ----
    float* halfmin = (float*)smemc;             // [256][4 wcn]  4 KB
    uint2* maskS   = (uint2*)(smemc + 4096);    // [256][4 wcn]  8 KB

    f32x4 c2v[4];
    #pragma unroll
    for (int n = 0; n < 4; n++)
        c2v[n] = *(const f32x4*)&cb2q[nt * 256 + wcn * 64 + n * 16 + (l4 << 2)];

    #pragma unroll
    for (int m = 0; m < 8; m++) {
        float v = 3.4e38f;
        #pragma unroll
        for (int n = 0; n < 4; n++)
            #pragma unroll
            for (int r = 0; r < 4; r++)
                v = fminf(v, fmaf(-2.f, acc[n][m][r], c2v[n][r]));
        v = fminf(v, __shfl_xor(v, 16));
        v = fminf(v, __shfl_xor(v, 32));
        if (l4 == 0) halfmin[(wr * 128 + m * 16 + l15) * 4 + wcn] = v;
    }
    __syncthreads();

    #pragma unroll
    for (int m = 0; m < 8; m++) {
        int rL = wr * 128 + m * 16 + l15;
        int pb = wcn & 2;
        float vt = fminf(halfmin[rL * 4 + pb], halfmin[rL * 4 + pb + 1]);
        float thrm = vt + W;
        uint blo = 0, bhi = 0;
        #pragma unroll
        for (int n = 0; n < 4; n++)
            #pragma unroll
            for (int r = 0; r < 4; r++) {
                float d = fmaf(-2.f, acc[n][m][r], c2v[n][r]);
                int bit = n * 16 + (l4 << 2) + r;
                if (d < thrm) { if (bit < 32) blo |= 1u << bit; else bhi |= 1u << (bit - 32); }
            }
        blo |= __shfl_xor(blo, 16); bhi |= __shfl_xor(bhi, 16);
        blo |= __shfl_xor(blo, 32); bhi |= __shfl_xor(bhi, 32);
        if (l4 == 0) maskS[rL * 4 + wcn] = make_uint2(blo, bhi);
    }
    __syncthreads();

    {
        int T = tid >> 8, rL = tid & 255;
        float vt = fminf(halfmin[rL * 4 + T * 2], halfmin[rL * 4 + T * 2 + 1]);
        uint2 lo = maskS[rL * 4 + T * 2], hi = maskS[rL * 4 + T * 2 + 1];
        size_t o = (size_t)(nt * 2 + T) * MM + mt * 256 + rL;
        blockv1[o] = vt;
        blockmask[o] = make_uint4(lo.x, lo.y, hi.x, hi.y);
    }
    #undef STAGET
    #undef LDAB
    #undef PHALL
}

// ---------------- combine + exact refine + update: ONE WAVE PER ROW, no barriers ----
// At q==QQ-1: writes quantized = x - new_resid directly (final fused).
__global__ __launch_bounds__(256) void crru_kernel(
    const float*  __restrict__ blockv1,
    const uint4*  __restrict__ blockmask,
    const float*  __restrict__ cbq,
    const float*  __restrict__ cb2q,
    const float*  __restrict__ xin,
    float*        __restrict__ resid,
    float*        __restrict__ idx_out,
    short8*       __restrict__ ah,
    int q, float W)
{
    __shared__ float rs[4][DD];          // 8 KB: per-wave resid row
    const int wid  = threadIdx.x >> 6;
    const int lane = threadIdx.x & 63;
    const int row  = blockIdx.x * 4 + wid;
    const int grp  = lane >> 4, gl = lane & 15;

    float v1 = 3.4e38f;
    uint4 mk = make_uint4(0, 0, 0, 0);
    if (lane < NTILES) {
        size_t o = (size_t)lane * MM + row;
        v1 = blockv1[o];
        mk = blockmask[o];
    }

    float* rrow = resid + (size_t)row * DD + lane * 8;
    float4 r0 = *(const float4*)rrow;
    float4 r1 = *(const float4*)(rrow + 4);
    *(float4*)&rs[wid][lane * 8]     = r0;
    *(float4*)&rs[wid][lane * 8 + 4] = r1;

    float g1 = v1;
    #pragma unroll
    for (int off = 32; off >= 1; off >>= 1) g1 = fminf(g1, __shfl_xor(g1, off));
    const float thr = g1 + W;

    unsigned long long act = __ballot((lane < NTILES) && (v1 < thr));

    float be = 3.4e38f; int bk = 0x7FFFFFFF;
    const float* rsw = rs[wid];

    auto eval4 = [&](int k0, int k1, int k2, int k3) {
        int kg = (grp == 0) ? k0 : (grp == 1) ? k1 : (grp == 2) ? k2 : k3;
        float d = 0.f;
        if (kg >= 0) {
            const float* cp = cbq + (size_t)kg * DD + gl * 32;
            const float* rp = rsw + gl * 32;
            #pragma unroll
            for (int j = 0; j < 8; j++) {
                float4 c = *(const float4*)(cp + j * 4);
                float4 r = *(const float4*)(rp + j * 4);
                d = fmaf(r.x, c.x, d); d = fmaf(r.y, c.y, d);
                d = fmaf(r.z, c.z, d); d = fmaf(r.w, c.w, d);
            }
        }
        #pragma unroll
        for (int off = 8; off >= 1; off >>= 1) d += __shfl_xor(d, off);
        #pragma unroll
        for (int g = 0; g < 4; g++) {
            float dg = __shfl(d, g * 16);
            int kg2 = (g == 0) ? k0 : (g == 1) ? k1 : (g == 2) ? k2 : k3;
            if (kg2 >= 0) {
                float e = fmaf(-2.f, dg, cb2q[kg2]);
                if (e < be || (e == be && kg2 < bk)) { be = e; bk = kg2; }
            }
        }
    };

    while (act) {
        int tile = __ffsll(act) - 1; act &= act - 1;
        uint m0 = __shfl((int)mk.x, tile), m1 = __shfl((int)mk.y, tile);
        uint m2 = __shfl((int)mk.z, tile), m3 = __shfl((int)mk.w, tile);
        unsigned long long lo = ((unsigned long long)m1 << 32) | m0;
        unsigned long long hi = ((unsigned long long)m3 << 32) | m2;
        int base = tile * 128;
        while (lo | hi) {
            int c0 = -1, c1 = -1, c2 = -1, c3 = -1;
            #define POP1(dst) \
                if (lo) { int b = __ffsll(lo) - 1; lo &= lo - 1; dst = base + b; } \
                else if (hi) { int b = __ffsll(hi) - 1; hi &= hi - 1; dst = base + 64 + b; }
            POP1(c0) POP1(c1) POP1(c2) POP1(c3)
            #undef POP1
            eval4(c0, c1, c2, c3);
        }
    }
    const int winner = bk;   // identical in all lanes

    if (lane == 0) {
        int b = row >> 11, l = row & (LL - 1);
        idx_out[((size_t)b * QQ + q) * LL + l] = (float)winner;
    }

    const float* cw = cbq + (size_t)winner * DD + lane * 8;
    float4 c0 = *(const float4*)cw;
    float4 c1 = *(const float4*)(cw + 4);
    float4 n0 = make_float4(r0.x - c0.x, r0.y - c0.y, r0.z - c0.z, r0.w - c0.w);
    float4 n1 = make_float4(r1.x - c1.x, r1.y - c1.y, r1.z - c1.z, r1.w - c1.w);

    if (q < QQ - 1) {
        *(float4*)rrow       = n0;
        *(float4*)(rrow + 4) = n1;
        short8 h;
        h[0] = (short)f2bf(n0.x); h[1] = (short)f2bf(n0.y);
        h[2] = (short)f2bf(n0.z); h[3] = (short)f2bf(n0.w);
        h[4] = (short)f2bf(n1.x); h[5] = (short)f2bf(n1.y);
        h[6] = (short)f2bf(n1.z); h[7] = (short)f2bf(n1.w);
        ah[(size_t)row * 64 + lane] = h;   // coalesced 1 KB/row
    } else {
        // final level: quantized = x - resid_final, written directly
        const float* xw = xin + (size_t)row * DD + lane * 8;
        float4 x0 = *(const float4*)xw;
        float4 x1 = *(const float4*)(xw + 4);
        *(float4*)rrow       = make_float4(x0.x - n0.x, x0.y - n0.y, x0.z - n0.z, x0.w - n0.w);
        *(float4*)(rrow + 4) = make_float4(x1.x - n1.x, x1.y - n1.y, x1.z - n1.z, x1.w - n1.w);
    }
}

extern "C" void kernel_launch(void* const* d_in, const int* in_sizes, int n_in,
                              void* d_out, int out_size, void* d_ws, size_t ws_size,
                              hipStream_t stream) {
    (void)in_sizes; (void)n_in; (void)out_size; (void)ws_size;
    const float* x  = (const float*)d_in[0];
    const float* cb = (const float*)d_in[1];
    float* out = (float*)d_out;

    float* idx_out = out;                           // BB*QQ*LL floats
    float* resid   = out + (size_t)BB * QQ * LL;    // doubles as quantized output

    char* w = (char*)d_ws;
    float*  cb2       = (float*)(w);                 // 64 KB
    float*  blockv1   = (float*)(w + 0x10000);       // 1 MB  -> ends 0x110000
    uint4*  blockmask = (uint4*)(w + 0x110000);      // 4 MB  -> ends 0x510000
    short8* ah        = (short8*)(w + 0x510000);     // 16 MB -> ends 0x1510000
    short8* bh2all    = (short8*)(w + 0x1510000);    // 16 MB -> ends 0x2510000 (~37 MB)

    bprep_kernel<<<QQ * KK / 4, 256, 0, stream>>>(cb, bh2all, cb2);  // all levels + norms, once
    aprep0_kernel<<<MM / 4, 256, 0, stream>>>(x, resid, ah);

    for (int q = 0; q < QQ; q++) {
        const float* cbq  = cb + (size_t)q * KK * DD;
        const float* c2q  = cb2 + (size_t)q * KK;
        const short8* bhq = bh2all + (size_t)q * KK * 64;
        const float W = 2.0f + 0.3f * q;   // proven coverage window (R7-R9)

        gemm_argmin_kernel<<<512, 512, 0, stream>>>(ah, bhq, c2q,
                                                    blockv1, blockmask, W);

        crru_kernel<<<MM / 4, 256, 0, stream>>>(blockv1, blockmask, cbq, c2q, x,
                                                resid, idx_out, ah, q, W);
    }
}

// Round 14
// 499.219 us; speedup vs baseline: 5.8505x; 5.8505x over previous
//
#include <hip/hip_runtime.h>

#define BB 8
#define LL 2048
#define DD 512
#define QQ 8
#define KK 2048
#define MM (BB*LL)      // 16384 points

#define NTILES 16       // 16 col-tiles of 128

typedef __attribute__((ext_vector_type(8))) short short8;
typedef __attribute__((ext_vector_type(4))) float f32x4;

#define GLDS(src, dst) __builtin_amdgcn_global_load_lds( \
    (const __attribute__((address_space(1))) void*)(src), \
    (__attribute__((address_space(3))) void*)(dst), 16, 0, 0)

#define BARX()  asm volatile("s_barrier" ::: "memory")
#define WAIT0() asm volatile("s_waitcnt vmcnt(0)" ::: "memory")

__device__ __forceinline__ ushort f2bf(float f) {
    uint u = __float_as_uint(f);
    u += 0x7FFFu + ((u >> 16) & 1u);
    return (ushort)(u >> 16);
}

// ---------------- B prep ALL LEVELS once + fused squared norms ----------------
__global__ __launch_bounds__(256) void bprep_kernel(const float* __restrict__ cb,
                                                    short8* __restrict__ bh2all,
                                                    float* __restrict__ cb2) {
    const int wid  = threadIdx.x >> 6;
    const int lane = threadIdx.x & 63;
    const int col  = blockIdx.x * 4 + wid;      // 0 .. QQ*KK-1
    const float* src = cb + (size_t)col * DD + lane * 8;
    float4 v0 = *(const float4*)src;
    float4 v1 = *(const float4*)(src + 4);
    short8 h;
    h[0] = (short)f2bf(v0.x); h[1] = (short)f2bf(v0.y);
    h[2] = (short)f2bf(v0.z); h[3] = (short)f2bf(v0.w);
    h[4] = (short)f2bf(v1.x); h[5] = (short)f2bf(v1.y);
    h[6] = (short)f2bf(v1.z); h[7] = (short)f2bf(v1.w);
    bh2all[(size_t)col * 64 + lane] = h;
    float s = v0.x*v0.x + v0.y*v0.y + v0.z*v0.z + v0.w*v0.w
            + v1.x*v1.x + v1.y*v1.y + v1.z*v1.z + v1.w*v1.w;
    #pragma unroll
    for (int off = 32; off >= 1; off >>= 1) s += __shfl_xor(s, off);
    if (lane == 0) cb2[col] = s;
}

// ---------------- level-0 A prep: resid <- x, ah <- bf16(x) [row][lane] ----------------
__global__ __launch_bounds__(256) void aprep0_kernel(const float* __restrict__ x,
                                                     float* __restrict__ resid,
                                                     short8* __restrict__ ah) {
    const int wid  = threadIdx.x >> 6;
    const int lane = threadIdx.x & 63;
    const int row  = blockIdx.x * 4 + wid;
    const float* src = x + (size_t)row * DD + lane * 8;
    float4 v0 = *(const float4*)src;
    float4 v1 = *(const float4*)(src + 4);
    float* dst = resid + (size_t)row * DD + lane * 8;
    *(float4*)dst       = v0;
    *(float4*)(dst + 4) = v1;
    short8 h;
    h[0] = (short)f2bf(v0.x); h[1] = (short)f2bf(v0.y);
    h[2] = (short)f2bf(v0.z); h[3] = (short)f2bf(v0.w);
    h[4] = (short)f2bf(v1.x); h[5] = (short)f2bf(v1.y);
    h[6] = (short)f2bf(v1.z); h[7] = (short)f2bf(v1.w);
    ah[(size_t)row * 64 + lane] = h;
}

// ---------------- 256x256 BK=64 bf16 GEMM + per-tile (v1, mask) — r8-proven ----------------
// 512 blocks x 512 thr (8 waves 2Mx4N, wave tile 128x64), 8 K-tiles, ONE panel per
// block (per-XCD L2 working set ~2.2MB, resident; two-panel variant thrashed L2).
// 1 barrier-pair per K-tile, compiler-scheduled body, XOR-swizzled GLDS staging.
__global__ __launch_bounds__(512, 2) void gemm_argmin_kernel(
    const short8* __restrict__ ah,
    const short8* __restrict__ bh2q,
    const float*  __restrict__ cb2q,
    float*        __restrict__ blockv1,    // [NTILES][MM]
    uint4*        __restrict__ blockmask,  // [NTILES][MM]
    float W)
{
    __shared__ char smemc[131072];   // [2 buf][A 32KB | B 32KB]

    const int id  = blockIdx.x;
    const int xcd = id & 7;
    const int s   = id >> 3;             // 0..63
    const int nt  = s & 7;               // 0..7 (256-col tiles)
    const int mt  = xcd * 8 + (s >> 3);  // 0..63 (256-row tiles), A reuse per XCD

    const int tid  = threadIdx.x;
    const int wid  = tid >> 6;
    const int lane = tid & 63;
    const int wr   = wid >> 2;           // rows [wr*128, +128)
    const int wcn  = wid & 3;            // cols [wcn*64, +64)
    const int l15  = lane & 15, l4 = lane >> 4;

    f32x4 acc[4][8];
    #pragma unroll
    for (int n = 0; n < 4; n++)
        #pragma unroll
        for (int m = 0; m < 8; m++) acc[n][m] = (f32x4){0.f, 0.f, 0.f, 0.f};

    const char* aSrc = (const char*)ah   + ((size_t)mt << 18);   // 256 rows x 1 KB
    const char* bSrc = (const char*)bh2q + ((size_t)nt << 18);

    #define STAGEQ(tt, bufn, p) do { \
        int g_ = (p) * 512 + tid; \
        int rL_ = g_ >> 3, st_ = g_ & 7; \
        int k_ = st_ ^ (rL_ & 7); \
        char* db_ = smemc + (bufn) * 65536 + ((p) * 512 + wid * 64) * 16; \
        GLDS(aSrc + (size_t)rL_ * 1024 + (tt) * 128 + k_ * 16, db_); \
        GLDS(bSrc + (size_t)rL_ * 1024 + (tt) * 128 + k_ * 16, db_ + 32768); \
    } while (0)

    short8 af[4][2], bf[4][2];

    #define LDA(mh) do { \
        _Pragma("unroll") for (int mm = 0; mm < 4; mm++) \
        _Pragma("unroll") for (int ks = 0; ks < 2; ks++) { \
            int rL_ = wr * 128 + ((mh) * 4 + mm) * 16 + l15; \
            int c_ = ks * 4 + l4; \
            af[mm][ks] = *(const short8*)(smemc + ab + rL_ * 128 + ((c_ ^ (rL_ & 7)) << 4)); \
        } } while (0)

    #define LDBALL() do { \
        _Pragma("unroll") for (int nn = 0; nn < 4; nn++) \
        _Pragma("unroll") for (int ks = 0; ks < 2; ks++) { \
            int cL_ = wcn * 64 + nn * 16 + l15; \
            int c_ = ks * 4 + l4; \
            bf[nn][ks] = *(const short8*)(smemc + ab + 32768 + cL_ * 128 + ((c_ ^ (cL_ & 7)) << 4)); \
        } } while (0)

    #define PH(mh) do { \
        __builtin_amdgcn_s_setprio(1); \
        _Pragma("unroll") for (int ks = 0; ks < 2; ks++) \
        _Pragma("unroll") for (int nn = 0; nn < 4; nn++) \
        _Pragma("unroll") for (int mm = 0; mm < 4; mm++) \
            acc[nn][(mh)*4+mm] = __builtin_amdgcn_mfma_f32_16x16x32_bf16( \
                bf[nn][ks], af[mm][ks], acc[nn][(mh)*4+mm], 0, 0, 0); \
        __builtin_amdgcn_s_setprio(0); \
    } while (0)

    STAGEQ(0, 0, 0); STAGEQ(0, 0, 1); STAGEQ(0, 0, 2); STAGEQ(0, 0, 3);
    WAIT0();
    BARX();

    for (int t = 0; t < 8; t++) {
        const uint ab = (uint)(t & 1) * 65536u;
        const int nbuf = (t & 1) ^ 1;
        if (t < 7) { STAGEQ(t + 1, nbuf, 0); STAGEQ(t + 1, nbuf, 1);
                     STAGEQ(t + 1, nbuf, 2); STAGEQ(t + 1, nbuf, 3); }
        LDBALL();
        LDA(0);
        PH(0);
        LDA(1);
        PH(1);
        if (t < 7) WAIT0();
        BARX();
    }

    // ---- mask epilogue (r8-verbatim) ----
    float* halfmin = (float*)smemc;             // [256][4 wcn]  4 KB
    uint2* maskS   = (uint2*)(smemc + 4096);    // [256][4 wcn]  8 KB

    f32x4 c2v[4];
    #pragma unroll
    for (int n = 0; n < 4; n++)
        c2v[n] = *(const f32x4*)&cb2q[nt * 256 + wcn * 64 + n * 16 + (l4 << 2)];

    #pragma unroll
    for (int m = 0; m < 8; m++) {
        float v = 3.4e38f;
        #pragma unroll
        for (int n = 0; n < 4; n++)
            #pragma unroll
            for (int r = 0; r < 4; r++)
                v = fminf(v, fmaf(-2.f, acc[n][m][r], c2v[n][r]));
        v = fminf(v, __shfl_xor(v, 16));
        v = fminf(v, __shfl_xor(v, 32));
        if (l4 == 0) halfmin[(wr * 128 + m * 16 + l15) * 4 + wcn] = v;
    }
    __syncthreads();

    #pragma unroll
    for (int m = 0; m < 8; m++) {
        int rL = wr * 128 + m * 16 + l15;
        int pb = wcn & 2;
        float vt = fminf(halfmin[rL * 4 + pb], halfmin[rL * 4 + pb + 1]);
        float thrm = vt + W;
        uint blo = 0, bhi = 0;
        #pragma unroll
        for (int n = 0; n < 4; n++)
            #pragma unroll
            for (int r = 0; r < 4; r++) {
                float d = fmaf(-2.f, acc[n][m][r], c2v[n][r]);
                int bit = n * 16 + (l4 << 2) + r;
                if (d < thrm) { if (bit < 32) blo |= 1u << bit; else bhi |= 1u << (bit - 32); }
            }
        blo |= __shfl_xor(blo, 16); bhi |= __shfl_xor(bhi, 16);
        blo |= __shfl_xor(blo, 32); bhi |= __shfl_xor(bhi, 32);
        if (l4 == 0) maskS[rL * 4 + wcn] = make_uint2(blo, bhi);
    }
    __syncthreads();

    {
        int T = tid >> 8, rL = tid & 255;
        float vt = fminf(halfmin[rL * 4 + T * 2], halfmin[rL * 4 + T * 2 + 1]);
        uint2 lo = maskS[rL * 4 + T * 2], hi = maskS[rL * 4 + T * 2 + 1];
        size_t o = (size_t)(nt * 2 + T) * MM + mt * 256 + rL;
        blockv1[o] = vt;
        blockmask[o] = make_uint4(lo.x, lo.y, hi.x, hi.y);
    }
    #undef STAGEQ
    #undef LDA
    #undef LDBALL
    #undef PH
}

// ---------------- combine + exact refine + update: ONE WAVE PER ROW, no barriers ----
// At q==QQ-1: writes quantized = x - new_resid directly (final fused).
__global__ __launch_bounds__(256) void crru_kernel(
    const float*  __restrict__ blockv1,
    const uint4*  __restrict__ blockmask,
    const float*  __restrict__ cbq,
    const float*  __restrict__ cb2q,
    const float*  __restrict__ xin,
    float*        __restrict__ resid,
    float*        __restrict__ idx_out,
    short8*       __restrict__ ah,
    int q, float W)
{
    __shared__ float rs[4][DD];          // 8 KB: per-wave resid row
    const int wid  = threadIdx.x >> 6;
    const int lane = threadIdx.x & 63;
    const int row  = blockIdx.x * 4 + wid;
    const int grp  = lane >> 4, gl = lane & 15;

    float v1 = 3.4e38f;
    uint4 mk = make_uint4(0, 0, 0, 0);
    if (lane < NTILES) {
        size_t o = (size_t)lane * MM + row;
        v1 = blockv1[o];
        mk = blockmask[o];
    }

    float* rrow = resid + (size_t)row * DD + lane * 8;
    float4 r0 = *(const float4*)rrow;
    float4 r1 = *(const float4*)(rrow + 4);
    *(float4*)&rs[wid][lane * 8]     = r0;
    *(float4*)&rs[wid][lane * 8 + 4] = r1;

    float g1 = v1;
    #pragma unroll
    for (int off = 32; off >= 1; off >>= 1) g1 = fminf(g1, __shfl_xor(g1, off));
    const float thr = g1 + W;

    unsigned long long act = __ballot((lane < NTILES) && (v1 < thr));

    float be = 3.4e38f; int bk = 0x7FFFFFFF;
    const float* rsw = rs[wid];

    auto eval4 = [&](int k0, int k1, int k2, int k3) {
        int kg = (grp == 0) ? k0 : (grp == 1) ? k1 : (grp == 2) ? k2 : k3;
        float d = 0.f;
        if (kg >= 0) {
            const float* cp = cbq + (size_t)kg * DD + gl * 32;
            const float* rp = rsw + gl * 32;
            #pragma unroll
            for (int j = 0; j < 8; j++) {
                float4 c = *(const float4*)(cp + j * 4);
                float4 r = *(const float4*)(rp + j * 4);
                d = fmaf(r.x, c.x, d); d = fmaf(r.y, c.y, d);
                d = fmaf(r.z, c.z, d); d = fmaf(r.w, c.w, d);
            }
        }
        #pragma unroll
        for (int off = 8; off >= 1; off >>= 1) d += __shfl_xor(d, off);
        #pragma unroll
        for (int g = 0; g < 4; g++) {
            float dg = __shfl(d, g * 16);
            int kg2 = (g == 0) ? k0 : (g == 1) ? k1 : (g == 2) ? k2 : k3;
            if (kg2 >= 0) {
                float e = fmaf(-2.f, dg, cb2q[kg2]);
                if (e < be || (e == be && kg2 < bk)) { be = e; bk = kg2; }
            }
        }
    };

    while (act) {
        int tile = __ffsll(act) - 1; act &= act - 1;
        uint m0 = __shfl((int)mk.x, tile), m1 = __shfl((int)mk.y, tile);
        uint m2 = __shfl((int)mk.z, tile), m3 = __shfl((int)mk.w, tile);
        unsigned long long lo = ((unsigned long long)m1 << 32) | m0;
        unsigned long long hi = ((unsigned long long)m3 << 32) | m2;
        int base = tile * 128;
        while (lo | hi) {
            int c0 = -1, c1 = -1, c2 = -1, c3 = -1;
            #define POP1(dst) \
                if (lo) { int b = __ffsll(lo) - 1; lo &= lo - 1; dst = base + b; } \
                else if (hi) { int b = __ffsll(hi) - 1; hi &= hi - 1; dst = base + 64 + b; }
            POP1(c0) POP1(c1) POP1(c2) POP1(c3)
            #undef POP1
            eval4(c0, c1, c2, c3);
        }
    }
    const int winner = bk;   // identical in all lanes

    if (lane == 0) {
        int b = row >> 11, l = row & (LL - 1);
        idx_out[((size_t)b * QQ + q) * LL + l] = (float)winner;
    }

    const float* cw = cbq + (size_t)winner * DD + lane * 8;
    float4 c0 = *(const float4*)cw;
    float4 c1 = *(const float4*)(cw + 4);
    float4 n0 = make_float4(r0.x - c0.x, r0.y - c0.y, r0.z - c0.z, r0.w - c0.w);
    float4 n1 = make_float4(r1.x - c1.x, r1.y - c1.y, r1.z - c1.z, r1.w - c1.w);

    if (q < QQ - 1) {
        *(float4*)rrow       = n0;
        *(float4*)(rrow + 4) = n1;
        short8 h;
        h[0] = (short)f2bf(n0.x); h[1] = (short)f2bf(n0.y);
        h[2] = (short)f2bf(n0.z); h[3] = (short)f2bf(n0.w);
        h[4] = (short)f2bf(n1.x); h[5] = (short)f2bf(n1.y);
        h[6] = (short)f2bf(n1.z); h[7] = (short)f2bf(n1.w);
        ah[(size_t)row * 64 + lane] = h;   // coalesced 1 KB/row
    } else {
        // final level: quantized = x - resid_final, written directly
        const float* xw = xin + (size_t)row * DD + lane * 8;
        float4 x0 = *(const float4*)xw;
        float4 x1 = *(const float4*)(xw + 4);
        *(float4*)rrow       = make_float4(x0.x - n0.x, x0.y - n0.y, x0.z - n0.z, x0.w - n0.w);
        *(float4*)(rrow + 4) = make_float4(x1.x - n1.x, x1.y - n1.y, x1.z - n1.z, x1.w - n1.w);
    }
}

extern "C" void kernel_launch(void* const* d_in, const int* in_sizes, int n_in,
                              void* d_out, int out_size, void* d_ws, size_t ws_size,
                              hipStream_t stream) {
    (void)in_sizes; (void)n_in; (void)out_size; (void)ws_size;
    const float* x  = (const float*)d_in[0];
    const float* cb = (const float*)d_in[1];
    float* out = (float*)d_out;

    float* idx_out = out;                           // BB*QQ*LL floats
    float* resid   = out + (size_t)BB * QQ * LL;    // doubles as quantized output

    char* w = (char*)d_ws;
    float*  cb2       = (float*)(w);                 // 64 KB
    float*  blockv1   = (float*)(w + 0x10000);       // 1 MB  -> ends 0x110000
    uint4*  blockmask = (uint4*)(w + 0x110000);      // 4 MB  -> ends 0x510000
    short8* ah        = (short8*)(w + 0x510000);     // 16 MB -> ends 0x1510000
    short8* bh2all    = (short8*)(w + 0x1510000);    // 16 MB -> ends 0x2510000 (~37 MB)

    bprep_kernel<<<QQ * KK / 4, 256, 0, stream>>>(cb, bh2all, cb2);  // all levels + norms, once
    aprep0_kernel<<<MM / 4, 256, 0, stream>>>(x, resid, ah);

    for (int q = 0; q < QQ; q++) {
        const float* cbq  = cb + (size_t)q * KK * DD;
        const float* c2q  = cb2 + (size_t)q * KK;
        const short8* bhq = bh2all + (size_t)q * KK * 64;
        const float W = 2.0f + 0.3f * q;   // proven coverage window (R7-R9)

        gemm_argmin_kernel<<<512, 512, 0, stream>>>(ah, bhq, c2q,
                                                    blockv1, blockmask, W);

        crru_kernel<<<MM / 4, 256, 0, stream>>>(blockv1, blockmask, cbq, c2q, x,
                                                resid, idx_out, ah, q, W);
    }
}

// Round 15
// 489.191 us; speedup vs baseline: 5.9704x; 1.0205x over previous
//
#include <hip/hip_runtime.h>

#define BB 8
#define LL 2048
#define DD 512
#define QQ 8
#define KK 2048
#define MM (BB*LL)      // 16384 points

#define NTILES 16       // 16 col-tiles of 128

typedef __attribute__((ext_vector_type(8))) short short8;
typedef __attribute__((ext_vector_type(4))) float f32x4;

#define GLDS(src, dst) __builtin_amdgcn_global_load_lds( \
    (const __attribute__((address_space(1))) void*)(src), \
    (__attribute__((address_space(3))) void*)(dst), 16, 0, 0)

#define BARX()   asm volatile("s_barrier" ::: "memory")
#define WAIT0()  asm volatile("s_waitcnt vmcnt(0)" ::: "memory")
#define WAITV2() asm volatile("s_waitcnt vmcnt(2)" ::: "memory")
#define WAITV4() asm volatile("s_waitcnt vmcnt(4)" ::: "memory")

__device__ __forceinline__ ushort f2bf(float f) {
    uint u = __float_as_uint(f);
    u += 0x7FFFu + ((u >> 16) & 1u);
    return (ushort)(u >> 16);
}

// ---------------- B prep ALL LEVELS once + fused squared norms ----------------
__global__ __launch_bounds__(256) void bprep_kernel(const float* __restrict__ cb,
                                                    short8* __restrict__ bh2all,
                                                    float* __restrict__ cb2) {
    const int wid  = threadIdx.x >> 6;
    const int lane = threadIdx.x & 63;
    const int col  = blockIdx.x * 4 + wid;      // 0 .. QQ*KK-1
    const float* src = cb + (size_t)col * DD + lane * 8;
    float4 v0 = *(const float4*)src;
    float4 v1 = *(const float4*)(src + 4);
    short8 h;
    h[0] = (short)f2bf(v0.x); h[1] = (short)f2bf(v0.y);
    h[2] = (short)f2bf(v0.z); h[3] = (short)f2bf(v0.w);
    h[4] = (short)f2bf(v1.x); h[5] = (short)f2bf(v1.y);
    h[6] = (short)f2bf(v1.z); h[7] = (short)f2bf(v1.w);
    bh2all[(size_t)col * 64 + lane] = h;
    float s = v0.x*v0.x + v0.y*v0.y + v0.z*v0.z + v0.w*v0.w
            + v1.x*v1.x + v1.y*v1.y + v1.z*v1.z + v1.w*v1.w;
    #pragma unroll
    for (int off = 32; off >= 1; off >>= 1) s += __shfl_xor(s, off);
    if (lane == 0) cb2[col] = s;
}

// ---------------- level-0 A prep: resid <- x, ah <- bf16(x) [row][lane] ----------------
__global__ __launch_bounds__(256) void aprep0_kernel(const float* __restrict__ x,
                                                     float* __restrict__ resid,
                                                     short8* __restrict__ ah) {
    const int wid  = threadIdx.x >> 6;
    const int lane = threadIdx.x & 63;
    const int row  = blockIdx.x * 4 + wid;
    const float* src = x + (size_t)row * DD + lane * 8;
    float4 v0 = *(const float4*)src;
    float4 v1 = *(const float4*)(src + 4);
    float* dst = resid + (size_t)row * DD + lane * 8;
    *(float4*)dst       = v0;
    *(float4*)(dst + 4) = v1;
    short8 h;
    h[0] = (short)f2bf(v0.x); h[1] = (short)f2bf(v0.y);
    h[2] = (short)f2bf(v0.z); h[3] = (short)f2bf(v0.w);
    h[4] = (short)f2bf(v1.x); h[5] = (short)f2bf(v1.y);
    h[6] = (short)f2bf(v1.z); h[7] = (short)f2bf(v1.w);
    ah[(size_t)row * 64 + lane] = h;
}

// ---------------- 256x256 BK=64 bf16 GEMM + per-tile (v1, mask) ----------------
// 4-phase counted-vmcnt schedule (faithful T3+T4 topology): per tile, 4 quadrant
// phases {vmcnt(4); s_barrier; issue 1 stage-unit (2 GLDS) for t+1; ds_read
// quadrant frags; setprio; 16 MFMA}. Stage-units regrouped by consumption
// (A: row-bit6, B: col-bit5; LDS cell mapping byte-identical to r14) and issued
// in consumption order [UA0,UB0,UB1,UA1] -> every load has 2-3 phases of cover,
// queue never drains below 4 in the main loop. P3: zero ds_reads, no barrier.
// Per-element K order (tile-ascending, ks0->ks1) == r14 -> masks bit-identical.
__global__ __launch_bounds__(512, 2) void gemm_argmin_kernel(
    const short8* __restrict__ ah,
    const short8* __restrict__ bh2q,
    const float*  __restrict__ cb2q,
    float*        __restrict__ blockv1,    // [NTILES][MM]
    uint4*        __restrict__ blockmask,  // [NTILES][MM]
    float W)
{
    __shared__ char smemc[131072];   // [2 buf][A 32KB | B 32KB]

    const int id  = blockIdx.x;
    const int xcd = id & 7;
    const int s   = id >> 3;             // 0..63
    const int nt  = s & 7;               // 0..7 (256-col tiles)
    const int mt  = xcd * 8 + (s >> 3);  // 0..63 (256-row tiles), A reuse per XCD

    const int tid  = threadIdx.x;
    const int wid  = tid >> 6;
    const int lane = tid & 63;
    const int wr   = wid >> 2;           // rows [wr*128, +128)
    const int wcn  = wid & 3;            // cols [wcn*64, +64)
    const int l15  = lane & 15, l4 = lane >> 4;

    f32x4 acc[4][8];
    #pragma unroll
    for (int n = 0; n < 4; n++)
        #pragma unroll
        for (int m = 0; m < 8; m++) acc[n][m] = (f32x4){0.f, 0.f, 0.f, 0.f};

    const char* aSrc = (const char*)ah   + ((size_t)mt << 18);   // 256 rows x 1 KB
    const char* bSrc = (const char*)bh2q + ((size_t)nt << 18);

    // stage-unit (isB, u): 128 rows/cols x 8 slots = 2 GLDS/thread.
    // A rows: bit6 == u ; B cols: bit5 == u. LDS cell (rc, st) at
    // (isB?32768:0) + rc*128 + st*16 holding src chunk st^(rc&7)  (r14-identical).
    #define STAGEU(tt, bufn, isB, u) do { \
        _Pragma("unroll") for (int j = 0; j < 2; j++) { \
            int riu0 = j * 64 + wid * 8;                /* wave-uniform */ \
            int riu  = riu0 + (lane >> 3); \
            int st   = lane & 7; \
            int rc  = (isB) ? (((riu  >> 5) << 6) + (u) * 32 + (riu  & 31)) \
                            : (((riu  >> 6) << 7) + (u) * 64 + (riu  & 63)); \
            int rc0 = (isB) ? (((riu0 >> 5) << 6) + (u) * 32 + (riu0 & 31)) \
                            : (((riu0 >> 6) << 7) + (u) * 64 + (riu0 & 63)); \
            int k_ = st ^ (rc & 7); \
            const char* s_ = ((isB) ? bSrc : aSrc) + (size_t)rc * 1024 \
                             + (tt) * 128 + k_ * 16; \
            GLDS(s_, smemc + (bufn) * 65536 + ((isB) ? 32768 : 0) + rc0 * 128); \
        } } while (0)

    short8 af[4][2], bf[4][2];

    #define LDA(mh) do { \
        _Pragma("unroll") for (int mm = 0; mm < 4; mm++) \
        _Pragma("unroll") for (int ks = 0; ks < 2; ks++) { \
            int rL_ = wr * 128 + ((mh) * 4 + mm) * 16 + l15; \
            int c_ = ks * 4 + l4; \
            af[mm][ks] = *(const short8*)(smemc + ab + rL_ * 128 + ((c_ ^ (rL_ & 7)) << 4)); \
        } } while (0)

    #define LDB2(nh) do { \
        _Pragma("unroll") for (int n2 = 0; n2 < 2; n2++) \
        _Pragma("unroll") for (int ks = 0; ks < 2; ks++) { \
            int nn = (nh) * 2 + n2; \
            int cL_ = wcn * 64 + nn * 16 + l15; \
            int c_ = ks * 4 + l4; \
            bf[nn][ks] = *(const short8*)(smemc + ab + 32768 + cL_ * 128 + ((c_ ^ (cL_ & 7)) << 4)); \
        } } while (0)

    // quadrant: 16 MFMA, per-element K order ks0->ks1 (r14-identical numerics)
    #define PHQ(mh, nh) do { \
        __builtin_amdgcn_s_setprio(1); \
        _Pragma("unroll") for (int ks = 0; ks < 2; ks++) \
        _Pragma("unroll") for (int n2 = 0; n2 < 2; n2++) \
        _Pragma("unroll") for (int mm = 0; mm < 4; mm++) \
            acc[(nh)*2+n2][(mh)*4+mm] = __builtin_amdgcn_mfma_f32_16x16x32_bf16( \
                bf[(nh)*2+n2][ks], af[mm][ks], acc[(nh)*2+n2][(mh)*4+mm], 0, 0, 0); \
        __builtin_amdgcn_s_setprio(0); \
    } while (0)

    // prologue: tile 0's four units in issue order (8 loads in flight)
    STAGEU(0, 0, 0, 0);   // UA0
    STAGEU(0, 0, 1, 0);   // UB0
    STAGEU(0, 0, 1, 1);   // UB1
    STAGEU(0, 0, 0, 1);   // UA1

    for (int t = 0; t < 7; t++) {
        const uint ab = (uint)(t & 1) * 65536u;
        const int nbuf = (t & 1) ^ 1;
        // P0 = Q(0,0): retire UA0(t),UB0(t)
        WAITV4(); BARX();
        STAGEU(t + 1, nbuf, 0, 0);
        LDA(0); LDB2(0);
        PHQ(0, 0);
        // P1 = Q(0,1): retire UB1(t)
        WAITV4(); BARX();
        STAGEU(t + 1, nbuf, 1, 0);
        LDB2(1);
        PHQ(0, 1);
        // P2 = Q(1,0): retire UA1(t)
        WAITV4(); BARX();
        STAGEU(t + 1, nbuf, 1, 1);
        LDA(1);
        PHQ(1, 0);
        // P3 = Q(1,1): all frags register-resident; no wait, no barrier
        STAGEU(t + 1, nbuf, 0, 1);
        PHQ(1, 1);
    }
    {   // tile 7 (buf1), no further issues; drain counts shift accordingly
        const uint ab = 65536u;
        WAITV4(); BARX();
        LDA(0); LDB2(0);
        PHQ(0, 0);
        WAITV2(); BARX();
        LDB2(1);
        PHQ(0, 1);
        WAIT0(); BARX();
        LDA(1);
        PHQ(1, 0);
        PHQ(1, 1);
    }

    // ---- mask epilogue (r14-verbatim; scratch in buf0, tile 7 read buf1) ----
    float* halfmin = (float*)smemc;             // [256][4 wcn]  4 KB
    uint2* maskS   = (uint2*)(smemc + 4096);    // [256][4 wcn]  8 KB

    f32x4 c2v[4];
    #pragma unroll
    for (int n = 0; n < 4; n++)
        c2v[n] = *(const f32x4*)&cb2q[nt * 256 + wcn * 64 + n * 16 + (l4 << 2)];

    #pragma unroll
    for (int m = 0; m < 8; m++) {
        float v = 3.4e38f;
        #pragma unroll
        for (int n = 0; n < 4; n++)
            #pragma unroll
            for (int r = 0; r < 4; r++)
                v = fminf(v, fmaf(-2.f, acc[n][m][r], c2v[n][r]));
        v = fminf(v, __shfl_xor(v, 16));
        v = fminf(v, __shfl_xor(v, 32));
        if (l4 == 0) halfmin[(wr * 128 + m * 16 + l15) * 4 + wcn] = v;
    }
    __syncthreads();

    #pragma unroll
    for (int m = 0; m < 8; m++) {
        int rL = wr * 128 + m * 16 + l15;
        int pb = wcn & 2;
        float vt = fminf(halfmin[rL * 4 + pb], halfmin[rL * 4 + pb + 1]);
        float thrm = vt + W;
        uint blo = 0, bhi = 0;
        #pragma unroll
        for (int n = 0; n < 4; n++)
            #pragma unroll
            for (int r = 0; r < 4; r++) {
                float d = fmaf(-2.f, acc[n][m][r], c2v[n][r]);
                int bit = n * 16 + (l4 << 2) + r;
                if (d < thrm) { if (bit < 32) blo |= 1u << bit; else bhi |= 1u << (bit - 32); }
            }
        blo |= __shfl_xor(blo, 16); bhi |= __shfl_xor(bhi, 16);
        blo |= __shfl_xor(blo, 32); bhi |= __shfl_xor(bhi, 32);
        if (l4 == 0) maskS[rL * 4 + wcn] = make_uint2(blo, bhi);
    }
    __syncthreads();

    {
        int T = tid >> 8, rL = tid & 255;
        float vt = fminf(halfmin[rL * 4 + T * 2], halfmin[rL * 4 + T * 2 + 1]);
        uint2 lo = maskS[rL * 4 + T * 2], hi = maskS[rL * 4 + T * 2 + 1];
        size_t o = (size_t)(nt * 2 + T) * MM + mt * 256 + rL;
        blockv1[o] = vt;
        blockmask[o] = make_uint4(lo.x, lo.y, hi.x, hi.y);
    }
    #undef STAGEU
    #undef LDA
    #undef LDB2
    #undef PHQ
}

// ---------------- combine + exact refine + update: ONE WAVE PER ROW, no barriers ----
// At q==QQ-1: writes quantized = x - new_resid directly (final fused).
__global__ __launch_bounds__(256) void crru_kernel(
    const float*  __restrict__ blockv1,
    const uint4*  __restrict__ blockmask,
    const float*  __restrict__ cbq,
    const float*  __restrict__ cb2q,
    const float*  __restrict__ xin,
    float*        __restrict__ resid,
    float*        __restrict__ idx_out,
    short8*       __restrict__ ah,
    int q, float W)
{
    __shared__ float rs[4][DD];          // 8 KB: per-wave resid row
    const int wid  = threadIdx.x >> 6;
    const int lane = threadIdx.x & 63;
    const int row  = blockIdx.x * 4 + wid;
    const int grp  = lane >> 4, gl = lane & 15;

    float v1 = 3.4e38f;
    uint4 mk = make_uint4(0, 0, 0, 0);
    if (lane < NTILES) {
        size_t o = (size_t)lane * MM + row;
        v1 = blockv1[o];
        mk = blockmask[o];
    }

    float* rrow = resid + (size_t)row * DD + lane * 8;
    float4 r0 = *(const float4*)rrow;
    float4 r1 = *(const float4*)(rrow + 4);
    *(float4*)&rs[wid][lane * 8]     = r0;
    *(float4*)&rs[wid][lane * 8 + 4] = r1;

    float g1 = v1;
    #pragma unroll
    for (int off = 32; off >= 1; off >>= 1) g1 = fminf(g1, __shfl_xor(g1, off));
    const float thr = g1 + W;

    unsigned long long act = __ballot((lane < NTILES) && (v1 < thr));

    float be = 3.4e38f; int bk = 0x7FFFFFFF;
    const float* rsw = rs[wid];

    auto eval4 = [&](int k0, int k1, int k2, int k3) {
        int kg = (grp == 0) ? k0 : (grp == 1) ? k1 : (grp == 2) ? k2 : k3;
        float d = 0.f;
        if (kg >= 0) {
            const float* cp = cbq + (size_t)kg * DD + gl * 32;
            const float* rp = rsw + gl * 32;
            #pragma unroll
            for (int j = 0; j < 8; j++) {
                float4 c = *(const float4*)(cp + j * 4);
                float4 r = *(const float4*)(rp + j * 4);
                d = fmaf(r.x, c.x, d); d = fmaf(r.y, c.y, d);
                d = fmaf(r.z, c.z, d); d = fmaf(r.w, c.w, d);
            }
        }
        #pragma unroll
        for (int off = 8; off >= 1; off >>= 1) d += __shfl_xor(d, off);
        #pragma unroll
        for (int g = 0; g < 4; g++) {
            float dg = __shfl(d, g * 16);
            int kg2 = (g == 0) ? k0 : (g == 1) ? k1 : (g == 2) ? k2 : k3;
            if (kg2 >= 0) {
                float e = fmaf(-2.f, dg, cb2q[kg2]);
                if (e < be || (e == be && kg2 < bk)) { be = e; bk = kg2; }
            }
        }
    };

    while (act) {
        int tile = __ffsll(act) - 1; act &= act - 1;
        uint m0 = __shfl((int)mk.x, tile), m1 = __shfl((int)mk.y, tile);
        uint m2 = __shfl((int)mk.z, tile), m3 = __shfl((int)mk.w, tile);
        unsigned long long lo = ((unsigned long long)m1 << 32) | m0;
        unsigned long long hi = ((unsigned long long)m3 << 32) | m2;
        int base = tile * 128;
        while (lo | hi) {
            int c0 = -1, c1 = -1, c2 = -1, c3 = -1;
            #define POP1(dst) \
                if (lo) { int b = __ffsll(lo) - 1; lo &= lo - 1; dst = base + b; } \
                else if (hi) { int b = __ffsll(hi) - 1; hi &= hi - 1; dst = base + 64 + b; }
            POP1(c0) POP1(c1) POP1(c2) POP1(c3)
            #undef POP1
            eval4(c0, c1, c2, c3);
        }
    }
    const int winner = bk;   // identical in all lanes

    if (lane == 0) {
        int b = row >> 11, l = row & (LL - 1);
        idx_out[((size_t)b * QQ + q) * LL + l] = (float)winner;
    }

    const float* cw = cbq + (size_t)winner * DD + lane * 8;
    float4 c0 = *(const float4*)cw;
    float4 c1 = *(const float4*)(cw + 4);
    float4 n0 = make_float4(r0.x - c0.x, r0.y - c0.y, r0.z - c0.z, r0.w - c0.w);
    float4 n1 = make_float4(r1.x - c1.x, r1.y - c1.y, r1.z - c1.z, r1.w - c1.w);

    if (q < QQ - 1) {
        *(float4*)rrow       = n0;
        *(float4*)(rrow + 4) = n1;
        short8 h;
        h[0] = (short)f2bf(n0.x); h[1] = (short)f2bf(n0.y);
        h[2] = (short)f2bf(n0.z); h[3] = (short)f2bf(n0.w);
        h[4] = (short)f2bf(n1.x); h[5] = (short)f2bf(n1.y);
        h[6] = (short)f2bf(n1.z); h[7] = (short)f2bf(n1.w);
        ah[(size_t)row * 64 + lane] = h;   // coalesced 1 KB/row
    } else {
        // final level: quantized = x - resid_final, written directly
        const float* xw = xin + (size_t)row * DD + lane * 8;
        float4 x0 = *(const float4*)xw;
        float4 x1 = *(const float4*)(xw + 4);
        *(float4*)rrow       = make_float4(x0.x - n0.x, x0.y - n0.y, x0.z - n0.z, x0.w - n0.w);
        *(float4*)(rrow + 4) = make_float4(x1.x - n1.x, x1.y - n1.y, x1.z - n1.z, x1.w - n1.w);
    }
}

extern "C" void kernel_launch(void* const* d_in, const int* in_sizes, int n_in,
                              void* d_out, int out_size, void* d_ws, size_t ws_size,
                              hipStream_t stream) {
    (void)in_sizes; (void)n_in; (void)out_size; (void)ws_size;
    const float* x  = (const float*)d_in[0];
    const float* cb = (const float*)d_in[1];
    float* out = (float*)d_out;

    float* idx_out = out;                           // BB*QQ*LL floats
    float* resid   = out + (size_t)BB * QQ * LL;    // doubles as quantized output

    char* w = (char*)d_ws;
    float*  cb2       = (float*)(w);                 // 64 KB
    float*  blockv1   = (float*)(w + 0x10000);       // 1 MB  -> ends 0x110000
    uint4*  blockmask = (uint4*)(w + 0x110000);      // 4 MB  -> ends 0x510000
    short8* ah        = (short8*)(w + 0x510000);     // 16 MB -> ends 0x1510000
    short8* bh2all    = (short8*)(w + 0x1510000);    // 16 MB -> ends 0x2510000 (~37 MB)

    bprep_kernel<<<QQ * KK / 4, 256, 0, stream>>>(cb, bh2all, cb2);  // all levels + norms, once
    aprep0_kernel<<<MM / 4, 256, 0, stream>>>(x, resid, ah);

    for (int q = 0; q < QQ; q++) {
        const float* cbq  = cb + (size_t)q * KK * DD;
        const float* c2q  = cb2 + (size_t)q * KK;
        const short8* bhq = bh2all + (size_t)q * KK * 64;
        const float W = 2.0f + 0.3f * q;   // proven coverage window (R7-R9)

        gemm_argmin_kernel<<<512, 512, 0, stream>>>(ah, bhq, c2q,
                                                    blockv1, blockmask, W);

        crru_kernel<<<MM / 4, 256, 0, stream>>>(blockv1, blockmask, cbq, c2q, x,
                                                resid, idx_out, ah, q, W);
    }
}